// Round 1
// baseline (100.504 us; speedup 1.0000x reference)
//
#include <hip/hip_runtime.h>

// Depthwise 5x5 SAME conv + gate residual: out = x*(alpha*conv + bias) + x
// x: (B=32, H=112, W=112, C=96) f32, NHWC. kernel: (5,5,96) f32.
// Strategy: one thread per (b, w, c) column; slide along H with a 5-slot
// ring of accumulators. Each input row is loaded once (5 w-taps), each tap
// coalesced across c. 25 FMAs/output. Center tap recycled for the residual.

#define CH 96
#define WI 112
#define HI 112
#define BATCH 32
#define ROW_STRIDE (WI * CH)        // 10752
#define IMG_STRIDE (HI * WI * CH)   // 1204224

__global__ __launch_bounds__(256) void dwconv_gate_kernel(
    const float* __restrict__ x,
    const float* __restrict__ kern,
    const float* __restrict__ alpha,
    const float* __restrict__ bias,
    float* __restrict__ out)
{
    const int gid = blockIdx.x * blockDim.x + threadIdx.x;
    // gid -> (b, w, c); c innermost for coalescing
    const int c  = gid % CH;
    const int bw = gid / CH;
    const int w  = bw % WI;
    const int b  = bw / WI;
    if (b >= BATCH) return;

    const float alphav = alpha[0];
    const float biasv  = bias[0];

    // Per-channel 5x5 weights into registers (statically indexed).
    float wt[25];
#pragma unroll
    for (int i = 0; i < 25; ++i) wt[i] = kern[i * CH + c];

    // Loop-invariant width-edge masks.
    bool mok[5];
#pragma unroll
    for (int dx = 0; dx < 5; ++dx) {
        const int ww = w + dx - 2;
        mok[dx] = (ww >= 0) && (ww < WI);
    }

    const float* px  = x   + (size_t)b * IMG_STRIDE + (size_t)w * CH + c;
    float*       po  = out + (size_t)b * IMG_STRIDE + (size_t)w * CH + c;

    // acc[j] accumulates output row h' = r - 2 + j at the start of iteration r.
    float acc[5] = {0.f, 0.f, 0.f, 0.f, 0.f};
    float xp1 = 0.f, xp2 = 0.f;  // center-tap history (delay 2) for residual

    for (int r = 0; r < HI + 2; ++r) {
        float t[5];
        if (r < HI) {
            const float* prow = px + (size_t)r * ROW_STRIDE;
#pragma unroll
            for (int dx = 0; dx < 5; ++dx)
                t[dx] = mok[dx] ? prow[(dx - 2) * CH] : 0.f;
        } else {
#pragma unroll
            for (int dx = 0; dx < 5; ++dx) t[dx] = 0.f;
        }

        // Row r contributes to output h' = r-2+j with weight row dy = 4-j.
#pragma unroll
        for (int j = 0; j < 5; ++j) {
            const int dy = 4 - j;
#pragma unroll
            for (int dx = 0; dx < 5; ++dx)
                acc[j] = fmaf(t[dx], wt[dy * 5 + dx], acc[j]);
        }

        if (r >= 2) {
            const float conv = acc[0];
            const float xc   = xp2;                 // x center of row r-2
            const float g    = fmaf(conv, alphav, biasv);
            po[(size_t)(r - 2) * ROW_STRIDE] = fmaf(g, xc, xc);
        }

        xp2 = xp1;
        xp1 = t[2];

        // Static ring shift (no runtime indexing -> stays in VGPRs).
        acc[0] = acc[1];
        acc[1] = acc[2];
        acc[2] = acc[3];
        acc[3] = acc[4];
        acc[4] = 0.f;
    }
}

extern "C" void kernel_launch(void* const* d_in, const int* in_sizes, int n_in,
                              void* d_out, int out_size, void* d_ws, size_t ws_size,
                              hipStream_t stream) {
    const float* x     = (const float*)d_in[0];
    const float* kern  = (const float*)d_in[1];
    const float* alpha = (const float*)d_in[2];
    const float* bias  = (const float*)d_in[3];
    float* out = (float*)d_out;

    const int total = BATCH * WI * CH;      // 344064, exact multiple of 256
    dim3 block(256);
    dim3 grid(total / 256);                 // 1344 blocks
    hipLaunchKernelGGL(dwconv_gate_kernel, grid, block, 0, stream,
                       x, kern, alpha, bias, out);
}

// Round 2
// 91.691 us; speedup vs baseline: 1.0961x; 1.0961x over previous
//
#include <hip/hip_runtime.h>

// Depthwise 5x5 SAME conv + gate residual: out = x*(alpha*conv + bias) + x
// x: (B=32, H=112, W=112, C=96) f32 NHWC. kernel: (5,5,96) f32.
//
// R2 changes vs R1 (latency-bound at 55% occupancy, 32% HBM):
//  - H split into NSPLIT=2 chunks per thread -> grid 1344 -> 2688 blocks
//    (42 waves/CU demand vs 32 cap -> full residency). Halo = +4 rows per
//    56-row chunk (+7% fetch).
//  - Software-pipelined row prefetch: next row's 5 taps issue BEFORE the
//    current row's 25 FMAs, so load latency drains behind compute instead
//    of an immediate vmcnt(0) stall.

#define CH 96
#define WI 112
#define HI 112
#define BATCH 32
#define NSPLIT 2
#define RH (HI / NSPLIT)            // 56 output rows per thread
#define ROW_STRIDE (WI * CH)        // 10752
#define IMG_STRIDE (HI * WI * CH)   // 1204224

__global__ __launch_bounds__(256) void dwconv_gate_kernel(
    const float* __restrict__ x,
    const float* __restrict__ kern,
    const float* __restrict__ alpha,
    const float* __restrict__ bias,
    float* __restrict__ out)
{
    const int gid = blockIdx.x * blockDim.x + threadIdx.x;
    // gid -> (b, chunk, w, c); c innermost for coalescing
    const int c     = gid % CH;
    const int r1    = gid / CH;
    const int w     = r1 % WI;
    const int r2    = r1 / WI;
    const int chunk = r2 % NSPLIT;
    const int b     = r2 / NSPLIT;
    if (b >= BATCH) return;

    const float alphav = alpha[0];
    const float biasv  = bias[0];

    // Per-channel 5x5 weights into registers (statically indexed). 9.6 KB
    // table -> L1-resident across the block.
    float wt[25];
#pragma unroll
    for (int i = 0; i < 25; ++i) wt[i] = kern[i * CH + c];

    // Loop-invariant width-edge masks.
    bool mok[5];
#pragma unroll
    for (int dx = 0; dx < 5; ++dx) {
        const int ww = w + dx - 2;
        mok[dx] = (ww >= 0) && (ww < WI);
    }

    const int h0 = chunk * RH;
    const float* px = x   + (size_t)b * IMG_STRIDE + (size_t)w * CH + c;
    float*       po = out + (size_t)b * IMG_STRIDE + (size_t)w * CH + c;

    // acc[j]: partial sum for output row rin-2+j at start of the iteration
    // that processes input row rin.
    float acc[5] = {0.f, 0.f, 0.f, 0.f, 0.f};
    float xp1 = 0.f, xp2 = 0.f;   // center-tap history (delay 2) for residual
    float t[5];

    // Preload first input row (h0 - 2).
    {
        const int rin = h0 - 2;
        const bool rok = (rin >= 0);           // rin < HI always holds here
        const float* prow = px + (ptrdiff_t)rin * ROW_STRIDE;
#pragma unroll
        for (int dx = 0; dx < 5; ++dx)
            t[dx] = (rok && mok[dx]) ? prow[(dx - 2) * CH] : 0.f;
    }

    for (int i = 0; i < RH + 4; ++i) {
        // ---- prefetch next input row (independent of the FMAs below) ----
        float tn[5];
        {
            const int rn  = h0 - 1 + i;        // (h0-2) + (i+1)
            const bool rok = (rn >= 0) && (rn < HI) && (i + 1 < RH + 4);
            const float* prow = px + (ptrdiff_t)rn * ROW_STRIDE;
#pragma unroll
            for (int dx = 0; dx < 5; ++dx)
                tn[dx] = (rok && mok[dx]) ? prow[(dx - 2) * CH] : 0.f;
        }

        // ---- 25 FMAs on the row loaded LAST iteration (regs ready) ----
#pragma unroll
        for (int j = 0; j < 5; ++j) {
#pragma unroll
            for (int dx = 0; dx < 5; ++dx)
                acc[j] = fmaf(t[dx], wt[(4 - j) * 5 + dx], acc[j]);
        }

        // ---- emit output row (h0 - 4 + i) once its window is complete ----
        if (i >= 4) {
            const float xc = xp2;              // x center of the output row
            const float g  = fmaf(acc[0], alphav, biasv);
            po[(ptrdiff_t)(h0 - 4 + i) * ROW_STRIDE] = fmaf(g, xc, xc);
        }

        // ---- static ring shifts (stay in VGPRs) ----
        xp2 = xp1;
        xp1 = t[2];
        acc[0] = acc[1];
        acc[1] = acc[2];
        acc[2] = acc[3];
        acc[3] = acc[4];
        acc[4] = 0.f;
#pragma unroll
        for (int dx = 0; dx < 5; ++dx) t[dx] = tn[dx];  // vmcnt waits here,
                                                        // AFTER the FMAs
    }
}

extern "C" void kernel_launch(void* const* d_in, const int* in_sizes, int n_in,
                              void* d_out, int out_size, void* d_ws, size_t ws_size,
                              hipStream_t stream) {
    const float* x     = (const float*)d_in[0];
    const float* kern  = (const float*)d_in[1];
    const float* alpha = (const float*)d_in[2];
    const float* bias  = (const float*)d_in[3];
    float* out = (float*)d_out;

    const int total = BATCH * NSPLIT * WI * CH;   // 688128 = 2688 * 256
    dim3 block(256);
    dim3 grid(total / 256);                       // 2688 blocks
    hipLaunchKernelGGL(dwconv_gate_kernel, grid, block, 0, stream,
                       x, kern, alpha, bias, out);
}

// Round 3
// 90.395 us; speedup vs baseline: 1.1118x; 1.0143x over previous
//
#include <hip/hip_runtime.h>

// Depthwise 5x5 SAME conv + gate residual: out = x*(alpha*conv + bias) + x
// x: (B=32, H=112, W=112, C=96) f32 NHWC. kernel: (5,5,96) f32.
//
// R3 change vs R2 (wave-slot quantization: 10752 waves vs 8192 slots ->
// 2 rounds, 2nd round 31% full -> 62% measured occupancy):
//  - NSPLIT=3 with uneven chunks (38/38/36 rows): 16128 waves = 1.97 x 8192
//    -> 98.4% packing across exactly 2 rounds. Halo +10.7% fetch.
//  - Row-prefetch software pipeline kept from R2.

#define CH 96
#define WI 112
#define HI 112
#define BATCH 32
#define NSPLIT 3
#define CHUNK_ROWS 38               // chunks: 38, 38, 36
#define ROW_STRIDE (WI * CH)        // 10752
#define IMG_STRIDE (HI * WI * CH)   // 1204224

__global__ __launch_bounds__(256) void dwconv_gate_kernel(
    const float* __restrict__ x,
    const float* __restrict__ kern,
    const float* __restrict__ alpha,
    const float* __restrict__ bias,
    float* __restrict__ out)
{
    const int gid = blockIdx.x * blockDim.x + threadIdx.x;
    // gid -> (b, chunk, w, c); c innermost for coalescing
    const int c     = gid % CH;
    const int r1    = gid / CH;
    const int w     = r1 % WI;
    const int r2    = r1 / WI;
    const int chunk = r2 % NSPLIT;
    const int b     = r2 / NSPLIT;
    if (b >= BATCH) return;

    const float alphav = alpha[0];
    const float biasv  = bias[0];

    // Per-channel 5x5 weights into registers (statically indexed).
    float wt[25];
#pragma unroll
    for (int i = 0; i < 25; ++i) wt[i] = kern[i * CH + c];

    // Loop-invariant width-edge masks.
    bool mok[5];
#pragma unroll
    for (int dx = 0; dx < 5; ++dx) {
        const int ww = w + dx - 2;
        mok[dx] = (ww >= 0) && (ww < WI);
    }

    const int h0   = chunk * CHUNK_ROWS;
    const int rows = (chunk == NSPLIT - 1) ? (HI - h0) : CHUNK_ROWS; // 38/38/36
    const int nit  = rows + 4;

    const float* px = x   + (size_t)b * IMG_STRIDE + (size_t)w * CH + c;
    float*       po = out + (size_t)b * IMG_STRIDE + (size_t)w * CH + c;

    // acc[j]: partial sum for output row rin-2+j at start of the iteration
    // that processes input row rin.
    float acc[5] = {0.f, 0.f, 0.f, 0.f, 0.f};
    float xp1 = 0.f, xp2 = 0.f;   // center-tap history (delay 2) for residual
    float t[5];

    // Preload first input row (h0 - 2).
    {
        const int rin = h0 - 2;
        const bool rok = (rin >= 0);           // rin < HI always holds here
        const float* prow = px + (ptrdiff_t)rin * ROW_STRIDE;
#pragma unroll
        for (int dx = 0; dx < 5; ++dx)
            t[dx] = (rok && mok[dx]) ? prow[(dx - 2) * CH] : 0.f;
    }

    for (int i = 0; i < nit; ++i) {
        // ---- prefetch next input row (independent of the FMAs below) ----
        float tn[5];
        {
            const int rn  = h0 - 1 + i;        // (h0-2) + (i+1)
            const bool rok = (rn >= 0) && (rn < HI) && (i + 1 < nit);
            const float* prow = px + (ptrdiff_t)rn * ROW_STRIDE;
#pragma unroll
            for (int dx = 0; dx < 5; ++dx)
                tn[dx] = (rok && mok[dx]) ? prow[(dx - 2) * CH] : 0.f;
        }

        // ---- 25 FMAs on the row loaded LAST iteration (regs ready) ----
#pragma unroll
        for (int j = 0; j < 5; ++j) {
#pragma unroll
            for (int dx = 0; dx < 5; ++dx)
                acc[j] = fmaf(t[dx], wt[(4 - j) * 5 + dx], acc[j]);
        }

        // ---- emit output row (h0 - 4 + i) once its window is complete ----
        if (i >= 4) {
            const float xc = xp2;              // x center of the output row
            const float g  = fmaf(acc[0], alphav, biasv);
            po[(ptrdiff_t)(h0 - 4 + i) * ROW_STRIDE] = fmaf(g, xc, xc);
        }

        // ---- static ring shifts (stay in VGPRs) ----
        xp2 = xp1;
        xp1 = t[2];
        acc[0] = acc[1];
        acc[1] = acc[2];
        acc[2] = acc[3];
        acc[3] = acc[4];
        acc[4] = 0.f;
#pragma unroll
        for (int dx = 0; dx < 5; ++dx) t[dx] = tn[dx];  // vmcnt waits here,
                                                        // AFTER the FMAs
    }
}

extern "C" void kernel_launch(void* const* d_in, const int* in_sizes, int n_in,
                              void* d_out, int out_size, void* d_ws, size_t ws_size,
                              hipStream_t stream) {
    const float* x     = (const float*)d_in[0];
    const float* kern  = (const float*)d_in[1];
    const float* alpha = (const float*)d_in[2];
    const float* bias  = (const float*)d_in[3];
    float* out = (float*)d_out;

    const int total = BATCH * NSPLIT * WI * CH;   // 1,032,192 = 4032 * 256
    dim3 block(256);
    dim3 grid(total / 256);                       // 4032 blocks, 16128 waves
    hipLaunchKernelGGL(dwconv_gate_kernel, grid, block, 0, stream,
                       x, kern, alpha, bias, out);
}